// Round 4
// baseline (180.107 us; speedup 1.0000x reference)
//
#include <hip/hip_runtime.h>

typedef __bf16 bf16x8 __attribute__((ext_vector_type(8)));
typedef float f32x16 __attribute__((ext_vector_type(16)));
typedef short short8 __attribute__((ext_vector_type(8)));

#define S 512
#define CH 16

#define ELT(v, c) ((c)==0 ? (v).x : (c)==1 ? (v).y : (c)==2 ? (v).z : (v).w)

__device__ __forceinline__ float swishf(float z) {
    return z * __builtin_amdgcn_rcpf(1.0f + __expf(-z));
}

// All GEMMs transposed: D = W^T * data (weights = A-operand).
// 32x32x16 maps (R2/R3-verified): A[row=l&31][k=(l>>5)*8+j], B[k=(l>>5)*8+j][col=l&31],
// D reg r: [row=(r&3)+8*(r>>2)+4*(l>>5)][col=l&31].
// GEMM1 fused perceive+W1: K=144, 9 steps; k-slot(s,hi,j) = neighborhood pos s=(dr*3+dc),
//   channel c=hi*8+j. Wbig[s][c][o] = sum_f K_f[dr][dc] * W1[c*5+f][o].
// GEMM2 (K=64, 4 steps): k-slot(t,hi,j) -> h1-feat (t>>1)*32 + 4*hi + (t&1)*16 + (j&3)+8*(j>>2)
// GEMM3 (K=32, 2 steps): k-slot(t,hi,j) -> h2-feat 4*hi + t*16 + (j&3)+8*(j>>2)
// ws shorts [0,12288): A-frags x 64 lanes x 8bf16: fi=0..17 GEMM1 (fi=n*9+s),
//   18..21 GEMM2, 22..23 GEMM3.  byte 24576: f32 biases b1[64] b2[32] b3[16].
__global__ void prep_weights(const float* __restrict__ W1, const float* __restrict__ b1,
                             const float* __restrict__ W2, const float* __restrict__ b2,
                             const float* __restrict__ W3, const float* __restrict__ b3,
                             short* __restrict__ wsf, float* __restrict__ wsb)
{
    int idx = blockIdx.x * 256 + threadIdx.x;
    if (idx < 12288) {
        int fi = idx >> 9, rem = idx & 511;
        int lane = rem >> 3, j = rem & 7;
        int col = lane & 31, hi = lane >> 5;
        int jp = (j & 3) + 8 * (j >> 2);
        float v;
        if (fi < 18) {
            int n = fi / 9, s = fi - n * 9;
            int dr = s / 3, dc = s - dr * 3;
            int c = hi * 8 + j;
            const float wgt0 = (dr == 1) ? 2.f : 1.f;          // [1,2,1][dr]
            const float wgt1 = (dc == 1) ? 2.f : 1.f;          // [1,2,1][dc]
            const float dlt0 = (float)(dr - 1);                // [-1,0,1][dr]
            const float dlt1 = (float)(dc - 1);                // [-1,0,1][dc]
            const float lapm[9] = {0.25f, 0.5f, 0.25f, 0.5f, -3.f, 0.5f, 0.25f, 0.5f, 0.25f};
            float kI  = (s == 4) ? 1.f : 0.f;
            float kdx = wgt0 * dlt1 * 0.125f;
            float kdy = dlt0 * wgt1 * 0.125f;
            float klp = lapm[s];
            float kav = 1.f / 9.f;
            const float* wr = W1 + (c * 5) * 64 + n * 32 + col;
            v = kI * wr[0] + kdx * wr[64] + kdy * wr[128] + klp * wr[192] + kav * wr[256];
        } else if (fi < 22) {
            int t = fi - 18;
            int rowW = (t >> 1) * 32 + 4 * hi + (t & 1) * 16 + jp;
            v = W2[rowW * 32 + col];
        } else {
            int t = fi - 22;
            int rowW = 4 * hi + t * 16 + jp;
            v = (col < 16) ? W3[rowW * 16 + col] : 0.0f;       // pad M 16->32
        }
        __bf16 b = (__bf16)v;
        wsf[idx] = __builtin_bit_cast(short, b);
    }
    if (blockIdx.x == 0) {
        int t = threadIdx.x;
        if (t < 64) wsb[t] = b1[t];
        else if (t < 96) wsb[t] = b2[t - 64];
        else if (t < 112) wsb[t] = b3[t - 96];
    }
}

__global__ __launch_bounds__(256, 4) void nca_fused(
    const float* __restrict__ x, const float* __restrict__ noise,
    const short* __restrict__ wsf, const float* __restrict__ wsb,
    float* __restrict__ out)
{
    __shared__ short wlds[12288];                       // 24 KB, weights only
    {
        const int4* src = reinterpret_cast<const int4*>(wsf);
        int4* dst = reinterpret_cast<int4*>(wlds);
        for (int i = threadIdx.x; i < 1536; i += 256) dst[i] = src[i];
    }
    __syncthreads();                                    // the only barrier

    const int tid = threadIdx.x;
    const int bid = blockIdx.x;
    const int st = bid & 15;                            // 16 strips of 32 cols
    const int rg = (bid >> 4) & 127;                    // 128 row groups of 4
    const int bb = bid >> 11;                           // batch
    const int wv = tid >> 6, lane = tid & 63;
    const int col = lane & 31, hi = lane >> 5;
    const int row = rg * 4 + wv;                        // each wave: one row x 32 px
    const int px0 = st * 32;

    // ---- im2col B-frags: frag s = x[row-1+dr][px+dc-1][hi*8 .. hi*8+7] as bf16 ----
    short8 bfr[9];
    {
        const float* xb = x + (size_t)bb * S * S * CH + hi * 8;
        const bool rowInt = (row > 0) && (row < S - 1);
        const bool colInt = (px0 != 0) && (px0 != 480);
        if (rowInt && colInt) {                         // fast path: 14/16 strips, interior rows
#pragma unroll
            for (int dr = 0; dr < 3; ++dr) {
                const float* rp = xb + ((size_t)(row - 1 + dr) * S + (px0 + col - 1)) * CH;
#pragma unroll
                for (int dc = 0; dc < 3; ++dc) {
                    float4 v0 = *reinterpret_cast<const float4*>(rp + dc * CH);
                    float4 v1 = *reinterpret_cast<const float4*>(rp + dc * CH + 4);
                    short8 f;
                    f[0] = __builtin_bit_cast(short, (__bf16)v0.x);
                    f[1] = __builtin_bit_cast(short, (__bf16)v0.y);
                    f[2] = __builtin_bit_cast(short, (__bf16)v0.z);
                    f[3] = __builtin_bit_cast(short, (__bf16)v0.w);
                    f[4] = __builtin_bit_cast(short, (__bf16)v1.x);
                    f[5] = __builtin_bit_cast(short, (__bf16)v1.y);
                    f[6] = __builtin_bit_cast(short, (__bf16)v1.z);
                    f[7] = __builtin_bit_cast(short, (__bf16)v1.w);
                    bfr[dr * 3 + dc] = f;
                }
            }
        } else {                                        // edge path (zero-pad = SAME conv)
#pragma unroll
            for (int dr = 0; dr < 3; ++dr) {
                int gr = row - 1 + dr;
                bool rok = (unsigned)gr < (unsigned)S;
                int grc = min(max(gr, 0), S - 1);
#pragma unroll
                for (int dc = 0; dc < 3; ++dc) {
                    int c = px0 + col - 1 + dc;
                    bool ok = rok && ((unsigned)c < (unsigned)S);
                    int cl = min(max(c, 0), S - 1);
                    const float* p = xb + ((size_t)grc * S + cl) * CH;
                    float4 v0 = *reinterpret_cast<const float4*>(p);
                    float4 v1 = *reinterpret_cast<const float4*>(p + 4);
                    if (!ok) { v0 = make_float4(0.f,0.f,0.f,0.f); v1 = v0; }
                    short8 f;
                    f[0] = __builtin_bit_cast(short, (__bf16)v0.x);
                    f[1] = __builtin_bit_cast(short, (__bf16)v0.y);
                    f[2] = __builtin_bit_cast(short, (__bf16)v0.z);
                    f[3] = __builtin_bit_cast(short, (__bf16)v0.w);
                    f[4] = __builtin_bit_cast(short, (__bf16)v1.x);
                    f[5] = __builtin_bit_cast(short, (__bf16)v1.y);
                    f[6] = __builtin_bit_cast(short, (__bf16)v1.z);
                    f[7] = __builtin_bit_cast(short, (__bf16)v1.w);
                    bfr[dr * 3 + dc] = f;
                }
            }
        }
    }

    const short8* wf = reinterpret_cast<const short8*>(wlds);

    // ---- GEMM1 (fused perceive+W1): h1[64f x 32px] = Wbig^T * im2col(x) ----
    f32x16 acc1[2];
#pragma unroll
    for (int n = 0; n < 2; ++n) {
        f32x16 acc = {};
#pragma unroll
        for (int s = 0; s < 9; ++s) {
            bf16x8 a = __builtin_bit_cast(bf16x8, wf[(n * 9 + s) * 64 + lane]);
            acc = __builtin_amdgcn_mfma_f32_32x32x16_bf16(a, __builtin_bit_cast(bf16x8, bfr[s]), acc, 0, 0, 0);
        }
        acc1[n] = acc;
    }

    // ---- swish + bias -> B2 frags (registers) ----
    short8 b2f[4];
#pragma unroll
    for (int t = 0; t < 4; ++t) {
        int n = t >> 1;
        float4 bq0 = *reinterpret_cast<const float4*>(wsb + n * 32 + 4 * hi + 16 * (t & 1));
        float4 bq1 = *reinterpret_cast<const float4*>(wsb + n * 32 + 4 * hi + 16 * (t & 1) + 8);
#pragma unroll
        for (int j = 0; j < 8; ++j) {
            float bias = (j < 4) ? ELT(bq0, j & 3) : ELT(bq1, j & 3);
            float h = swishf(acc1[n][(t & 1) * 8 + j] + bias);
            b2f[t][j] = __builtin_bit_cast(short, (__bf16)h);
        }
    }

    // ---- GEMM2: h2[32f x 32px] = W2^T * h1 ----
    f32x16 acc2 = {};
#pragma unroll
    for (int t = 0; t < 4; ++t) {
        bf16x8 a = __builtin_bit_cast(bf16x8, wf[(18 + t) * 64 + lane]);
        acc2 = __builtin_amdgcn_mfma_f32_32x32x16_bf16(a, __builtin_bit_cast(bf16x8, b2f[t]), acc2, 0, 0, 0);
    }

    short8 b3f[2];
#pragma unroll
    for (int t = 0; t < 2; ++t) {
        float4 cq0 = *reinterpret_cast<const float4*>(wsb + 64 + 4 * hi + 16 * t);
        float4 cq1 = *reinterpret_cast<const float4*>(wsb + 64 + 4 * hi + 16 * t + 8);
#pragma unroll
        for (int j = 0; j < 8; ++j) {
            float bias = (j < 4) ? ELT(cq0, j & 3) : ELT(cq1, j & 3);
            float h = swishf(acc2[t * 8 + j] + bias);
            b3f[t][j] = __builtin_bit_cast(short, (__bf16)h);
        }
    }

    // ---- GEMM3: dx[16f x 32px] = W3^T(pad32) * h2 ----
    f32x16 acc3 = {};
#pragma unroll
    for (int t = 0; t < 2; ++t) {
        bf16x8 a = __builtin_bit_cast(bf16x8, wf[(22 + t) * 64 + lane]);
        acc3 = __builtin_amdgcn_mfma_f32_32x32x16_bf16(a, __builtin_bit_cast(bf16x8, b3f[t]), acc3, 0, 0, 0);
    }

    // ---- epilogue: reg r -> ch = 4*hi + (r&3) + 8*(r>>2); coalesced float4 x2 ----
    size_t pix = ((size_t)(bb * S + row)) * S + px0 + col;
    float msk = (noise[pix] <= 0.5f) ? 1.f : 0.f;
    float4 bA = *reinterpret_cast<const float4*>(wsb + 96 + 4 * hi);
    float4 bB = *reinterpret_cast<const float4*>(wsb + 96 + 8 + 4 * hi);
    const float* xp = x + pix * CH;
    float4 c0 = *reinterpret_cast<const float4*>(xp + 4 * hi);
    float4 c1 = *reinterpret_cast<const float4*>(xp + 8 + 4 * hi);
    float4 o0, o1;
    o0.x = c0.x + (acc3[0] + bA.x) * msk;
    o0.y = c0.y + (acc3[1] + bA.y) * msk;
    o0.z = c0.z + (acc3[2] + bA.z) * msk;
    o0.w = c0.w + (acc3[3] + bA.w) * msk;
    o1.x = c1.x + (acc3[4] + bB.x) * msk;
    o1.y = c1.y + (acc3[5] + bB.y) * msk;
    o1.z = c1.z + (acc3[6] + bB.z) * msk;
    o1.w = c1.w + (acc3[7] + bB.w) * msk;
    *reinterpret_cast<float4*>(out + pix * CH + 4 * hi) = o0;
    *reinterpret_cast<float4*>(out + pix * CH + 8 + 4 * hi) = o1;
}

extern "C" void kernel_launch(void* const* d_in, const int* in_sizes, int n_in,
                              void* d_out, int out_size, void* d_ws, size_t ws_size,
                              hipStream_t stream)
{
    const float* x     = (const float*)d_in[0];
    const float* noise = (const float*)d_in[1];
    const float* W1    = (const float*)d_in[2];
    const float* b1    = (const float*)d_in[3];
    const float* W2    = (const float*)d_in[4];
    const float* b2    = (const float*)d_in[5];
    const float* W3    = (const float*)d_in[6];
    const float* b3    = (const float*)d_in[7];
    short* wsf = (short*)d_ws;
    float* wsb = (float*)((char*)d_ws + 24576);
    float* out = (float*)d_out;

    hipLaunchKernelGGL(prep_weights, dim3(48), dim3(256), 0, stream,
                       W1, b1, W2, b2, W3, b3, wsf, wsb);
    hipLaunchKernelGGL(nca_fused, dim3(4 * 128 * 16), dim3(256), 0, stream,
                       x, noise, wsf, wsb, out);
}